// Round 7
// baseline (28077.838 us; speedup 1.0000x reference)
//
#include <hip/hip_runtime.h>
#include <hip/hip_bf16.h>
#include <math.h>

#define E_ 7
#define B_ 50
#define T_ 100
#define D_ 128
#define A_ 32
#define L_ 256
#define H_ 1024
#define C_ 128
#define EB_ 350
#define TB_ 5000
#define SQRTH 0.31622776601683794f
#define NWG 256

typedef __attribute__((ext_vector_type(8))) short s8v;
typedef __attribute__((ext_vector_type(4))) float f32x4;
typedef _Float16 f16x2 __attribute__((ext_vector_type(2)));
typedef __hip_bfloat16 bf16;

#define MFMA __builtin_amdgcn_mfma_f32_16x16x32_bf16

__device__ __forceinline__ int lswz(int row, int ck) {
  return ((ck & ~7) | ((ck ^ row) & 7)) << 3;
}

struct BG {
  const bf16* A[8];
  const bf16* W[8];
  const float* bias[8];
  float* Cf[8];
  bf16* Cb[8];
};

// ---------------- bf16 MFMA GEMM (validated round 2) ----------------
template<int BM, int ACT, int OUT>
__global__ __launch_bounds__(256)
void bgemm(BG g, int M, int K, int lda, int ldw, int ldc) {
  __shared__ short As[BM * 64];
  __shared__ short Ws[128 * 64];
  const short* Ap = (const short*)g.A[blockIdx.z];
  const short* Wp = (const short*)g.W[blockIdx.z];
  const int bm = blockIdx.x * BM, bn = blockIdx.y * 128;
  const int tid = threadIdx.x;
  const int wv = tid >> 6, lane = tid & 63;
  const int wm0 = (wv >> 1) * (BM / 2), wn0 = (wv & 1) * 64;
  const int l15 = lane & 15, l4 = lane >> 4;
  constexpr int FM = BM / 32;
  constexpr int AI = BM / 32;
  f32x4 acc[FM][4] = {};
  for (int k0 = 0; k0 < K; k0 += 64) {
    s8v av[AI], wvv[4];
#pragma unroll
    for (int i = 0; i < AI; ++i) {
      const int c = tid + i * 256, r = c >> 3, ck = c & 7;
      s8v v = {};
      if (bm + r < M) v = *(const s8v*)(Ap + (size_t)(bm + r) * lda + k0 + ck * 8);
      av[i] = v;
    }
#pragma unroll
    for (int i = 0; i < 4; ++i) {
      const int c = tid + i * 256, r = c >> 3, ck = c & 7;
      wvv[i] = *(const s8v*)(Wp + (size_t)(bn + r) * ldw + k0 + ck * 8);
    }
    __syncthreads();
#pragma unroll
    for (int i = 0; i < AI; ++i) {
      const int c = tid + i * 256, r = c >> 3, ck = c & 7;
      *(s8v*)(As + r * 64 + ((ck ^ (r & 7)) << 3)) = av[i];
    }
#pragma unroll
    for (int i = 0; i < 4; ++i) {
      const int c = tid + i * 256, r = c >> 3, ck = c & 7;
      *(s8v*)(Ws + r * 64 + ((ck ^ (r & 7)) << 3)) = wvv[i];
    }
    __syncthreads();
#pragma unroll
    for (int ks = 0; ks < 2; ++ks) {
      s8v af[FM], bfr[4];
#pragma unroll
      for (int m = 0; m < FM; ++m) {
        const int r = wm0 + m * 16 + l15, ck = ks * 4 + l4;
        af[m] = *(const s8v*)(As + r * 64 + ((ck ^ (r & 7)) << 3));
      }
#pragma unroll
      for (int n = 0; n < 4; ++n) {
        const int r = wn0 + n * 16 + l15, ck = ks * 4 + l4;
        bfr[n] = *(const s8v*)(Ws + r * 64 + ((ck ^ (r & 7)) << 3));
      }
#pragma unroll
      for (int m = 0; m < FM; ++m)
#pragma unroll
        for (int n = 0; n < 4; ++n)
          acc[m][n] = MFMA(af[m], bfr[n], acc[m][n], 0, 0, 0);
    }
    __syncthreads();
  }
  const float* bias = g.bias[blockIdx.z];
  float* Cf = g.Cf[blockIdx.z];
  bf16* Cb = g.Cb[blockIdx.z];
#pragma unroll
  for (int n = 0; n < 4; ++n) {
    const int col = bn + wn0 + n * 16 + l15;
    const float bv = bias ? bias[col] : 0.f;
#pragma unroll
    for (int m = 0; m < FM; ++m) {
#pragma unroll
      for (int j = 0; j < 4; ++j) {
        const int row = bm + wm0 + m * 16 + l4 * 4 + j;
        if (row < M) {
          float v = acc[m][n][j] + bv;
          if (ACT == 1) v = fmaxf(v, 0.f);
          if (ACT == 2) v = tanhf(v);
          if (OUT == 0) Cf[(size_t)row * ldc + col] = v;
          if (OUT == 1) Cb[(size_t)row * ldc + col] = __float2bfloat16(v);
        }
      }
    }
  }
}

// ---------------- conversions / packing (validated round 6) ----------------
__global__ __launch_bounds__(256)
void cvtT_kernel(const float* __restrict__ src, bf16* __restrict__ dst,
                 int K, int N, long ss, long ds) {
  __shared__ float t[32][33];
  src += (size_t)blockIdx.z * ss;
  dst += (size_t)blockIdx.z * ds;
  const int n0 = blockIdx.x * 32, k0 = blockIdx.y * 32;
  const int tx = threadIdx.x & 31, ty = threadIdx.x >> 5;
#pragma unroll
  for (int i = 0; i < 4; ++i)
    t[ty + 8 * i][tx] = src[(size_t)(k0 + ty + 8 * i) * N + n0 + tx];
  __syncthreads();
#pragma unroll
  for (int i = 0; i < 4; ++i)
    dst[(size_t)(n0 + ty + 8 * i) * K + k0 + tx] = __float2bfloat16(t[tx][ty + 8 * i]);
}

struct B4 { bf16 a, b, c, d; };
__global__ __launch_bounds__(256)
void cvt_kernel(const float* __restrict__ s, bf16* __restrict__ d, int n4) {
  const int i = blockIdx.x * 256 + threadIdx.x;
  if (i < n4) {
    const float4 v = ((const float4*)s)[i];
    B4 o = {__float2bfloat16(v.x), __float2bfloat16(v.y),
            __float2bfloat16(v.z), __float2bfloat16(v.w)};
    ((B4*)d)[i] = o;
  }
}

__global__ __launch_bounds__(256)
void packW(const float* __restrict__ src, bf16* __restrict__ dst, int K, int N) {
  const int idx = blockIdx.x * 256 + threadIdx.x;
  if (idx >= K * N) return;
  const int k = idx / N, n = idx - k * N;
  const size_t fo = ((size_t)(n >> 4) * (K >> 5) + (k >> 5)) * 512 +
                    (((k >> 3) & 3) << 7) + ((n & 15) << 3) + (k & 7);
  dst[fo] = __float2bfloat16(src[idx]);
}

__global__ __launch_bounds__(256)
void packWz(const float* __restrict__ act_w, bf16* __restrict__ hi, bf16* __restrict__ lo) {
  const int idx = blockIdx.x * 256 + threadIdx.x;
  if (idx >= E_ * 65536) return;
  const int e = idx >> 16, rem = idx & 65535, k = rem >> 8, n = rem & 255;
  const float w = act_w[(size_t)e * 416 * 256 + (size_t)k * 256 + n];
  const bf16 h = __float2bfloat16(w);
  const size_t fo = (size_t)e * 65536 + ((size_t)(n >> 4) * 8 + (k >> 5)) * 512 +
                    (((k >> 3) & 3) << 7) + ((n & 15) << 3) + (k & 7);
  hi[fo] = h;
  lo[fo] = __float2bfloat16(w - __bfloat162float(h));
}

__global__ __launch_bounds__(256)
void ax_build(const float* __restrict__ actions, const float* __restrict__ xs,
              bf16* __restrict__ dst) {
  const int idx = blockIdx.x * 256 + threadIdx.x;
  if (idx >= E_ * TB_ * 192) return;
  const int k = idx % 192;
  const int r = (idx / 192) % TB_;
  const int e = idx / (192 * TB_);
  float v = 0.f;
  if (k < 32) v = actions[((size_t)e * TB_ + r) * A_ + k];
  else if (k < 160) v = xs[((size_t)e * TB_ + r) * D_ + (k - 32)];
  dst[idx] = __float2bfloat16(v);
}

__global__ __launch_bounds__(256)
void waxT_build(const float* __restrict__ act_w, bf16* __restrict__ dst) {
  const int idx = blockIdx.x * 256 + threadIdx.x;
  if (idx >= E_ * 256 * 192) return;
  const int k = idx % 192;
  const int n = (idx / 192) % 256;
  const int e = idx / (192 * 256);
  float v = (k < 160) ? act_w[(size_t)e * 416 * 256 + (size_t)(256 + k) * 256 + n] : 0.f;
  dst[idx] = __float2bfloat16(v);
}

__global__ __launch_bounds__(256)
void gpack_build(const float* __restrict__ gw1, const float* __restrict__ gb1,
                 const float* __restrict__ gw2, _Float16* __restrict__ dst) {
  const int idx = blockIdx.x * 256 + threadIdx.x;
  if (idx >= 256 * 3 * 1024) return;
  const int l = idx / 3072, rem = idx - l * 3072, arr = rem >> 10, h = rem & 1023;
  const float* s = arr == 0 ? gw1 : (arr == 1 ? gb1 : gw2);
  dst[idx] = (_Float16)s[(size_t)l * 1024 + h];
}

// ---------------- q/KL (+z0 split hi/lo) ----------------
__global__ __launch_bounds__(256)
void qkl_kernel(const float* __restrict__ ctx, int rows, int row_off, int ctx_estride,
                const float* __restrict__ qw, const float* __restrict__ qb,
                const float* __restrict__ pm, const float* __restrict__ pl,
                const float* __restrict__ eps0, bf16* __restrict__ z0hi,
                bf16* __restrict__ z0lo, float* __restrict__ logqp) {
  __shared__ float cx[16][128];
  __shared__ float red[16];
  const int e = blockIdx.y;
  const int r0 = blockIdx.x * 16;
  const int tid = threadIdx.x;
  {
    const int r = tid >> 4, c = (tid & 15) * 8;
    float4 v0 = make_float4(0.f, 0.f, 0.f, 0.f), v1 = v0;
    if (r0 + r < rows) {
      const float* src = ctx + (size_t)e * ctx_estride + (size_t)(r0 + r) * C_ + c;
      v0 = *(const float4*)src;
      v1 = *(const float4*)(src + 4);
    }
    *(float4*)&cx[r][c] = v0;
    *(float4*)&cx[r][c + 4] = v1;
  }
  if (tid < 16) red[tid] = 0.f;
  __syncthreads();
  const int j = tid;
  const float* w = qw + (size_t)e * C_ * 512;
  float am_[16] = {};
  float al_[16] = {};
  for (int k0 = 0; k0 < C_; k0 += 4) {
    float wm[4], wl[4];
#pragma unroll
    for (int q = 0; q < 4; ++q) {
      wm[q] = w[(size_t)(k0 + q) * 512 + j];
      wl[q] = w[(size_t)(k0 + q) * 512 + 256 + j];
    }
#pragma unroll
    for (int r = 0; r < 16; ++r) {
      const float4 cv = *(const float4*)&cx[r][k0];
      const float cc[4] = {cv.x, cv.y, cv.z, cv.w};
#pragma unroll
      for (int q = 0; q < 4; ++q) {
        am_[r] = fmaf(cc[q], wm[q], am_[r]);
        al_[r] = fmaf(cc[q], wl[q], al_[r]);
      }
    }
  }
  const float qbm = qb[(size_t)e * 512 + j];
  const float qbl = qb[(size_t)e * 512 + 256 + j];
  const float pmv = pm[(size_t)e * L_ + j];
  const float plv = pl[(size_t)e * L_ + j];
  const float inv2e = 0.5f * expf(-2.f * plv);
#pragma unroll
  for (int r = 0; r < 16; ++r) {
    float kl = 0.f;
    if (r0 + r < rows) {
      const float qm_ = am_[r] + qbm;
      const float ql_ = al_[r] + qbl;
      const float dm = qm_ - pmv;
      kl = plv - ql_ + (expf(2.f * ql_) + dm * dm) * inv2e - 0.5f;
      const int gi = row_off + r0 + r;
      if (gi < B_) {
        const size_t zi = ((size_t)e * B_ + gi) * L_ + j;
        const float z0 = qm_ + expf(ql_) * eps0[zi];
        const bf16 h = __float2bfloat16(z0);
        z0hi[zi] = h;
        z0lo[zi] = __float2bfloat16(z0 - __bfloat162float(h));
      }
    }
    for (int off = 32; off; off >>= 1) kl += __shfl_xor(kl, off, 64);
    if ((tid & 63) == 0) atomicAdd(&red[r], kl);
  }
  __syncthreads();
  if (tid < 16 && r0 + tid < rows) atomicAdd(&logqp[e], red[tid] * (1.0f / B_));
}

// ---------------- persistent scan ----------------
struct SK {
  const bf16 *wzh, *wzl, *w1f, *w2f, *w3f;
  const _Float16* gpk;
  const float *fb1, *hb1, *fb2, *hb2, *fb3, *hb3, *gb2;
  const float *axw, *dw;
  float *zP, *gv;
  bf16 *zPb, *fh1, *fh2, *zhi, *zlo, *zs_bf;
  float* logqp;
  unsigned* bar;  // leaf[16]@stride32, root@512, rel[256]@544+wg*32
};

// contention-free barrier: tree arrival + per-WG release lines (128B apart)
__device__ __forceinline__ void gsync(unsigned* bar, unsigned ph, int tid, int wg,
                                      int* sRel) {
  __threadfence();
  __syncthreads();
  if (tid == 0) {
    *sRel = 0;
    const unsigned v = __hip_atomic_fetch_add(&bar[(wg >> 4) * 32], 1u,
                                              __ATOMIC_RELAXED, __HIP_MEMORY_SCOPE_AGENT);
    if (v + 1u == ph * 16u) {
      const unsigned r = __hip_atomic_fetch_add(&bar[512], 1u,
                                                __ATOMIC_RELAXED, __HIP_MEMORY_SCOPE_AGENT);
      if (r + 1u == ph * 16u) *sRel = 1;
    }
  }
  __syncthreads();
  if (*sRel)
    __hip_atomic_store(&bar[544 + tid * 32], ph, __ATOMIC_RELAXED, __HIP_MEMORY_SCOPE_AGENT);
  if (tid == 0) {
    while (__hip_atomic_load(&bar[544 + wg * 32], __ATOMIC_RELAXED,
                             __HIP_MEMORY_SCOPE_AGENT) < ph)
      __builtin_amdgcn_s_sleep(8);
  }
  __syncthreads();
  __threadfence();
}

// g-tile: 16 rows x 64 l-cols; thread=(lloc,hq); fp16 packed (validated round 6)
__device__ void g_tile(const SK& a, int gt, int tid) {
  const int rb = gt >> 2, cb = gt & 3;
  const int r0 = rb * 16, c0 = cb * 64;
  const int lloc = tid >> 2, hq = tid & 3;
  const _Float16* gl = a.gpk + (size_t)(c0 + lloc) * 3072 + hq * 256;
  f16x2 z2[16];
#pragma unroll
  for (int r = 0; r < 16; ++r) {
    const float zf = (r0 + r < EB_) ? a.zP[(size_t)(r0 + r) * 256 + c0 + lloc] : 0.f;
    const _Float16 zh_ = (_Float16)zf;
    z2[r] = f16x2{zh_, zh_};
  }
  float ga[16] = {};
  for (int hp = 0; hp < 128; ++hp) {
    const f16x2 w1v = *(const f16x2*)(gl + 2 * hp);
    const f16x2 b1v = *(const f16x2*)(gl + 1024 + 2 * hp);
    const f16x2 w2v = *(const f16x2*)(gl + 2048 + 2 * hp);
#pragma unroll
    for (int r = 0; r < 16; ++r) {
      f16x2 tt = z2[r] * w1v + b1v;
#if __has_builtin(__builtin_elementwise_max)
      const f16x2 zz = {};
      tt = __builtin_elementwise_max(tt, zz);
#else
      tt[0] = tt[0] > (_Float16)0 ? tt[0] : (_Float16)0;
      tt[1] = tt[1] > (_Float16)0 ? tt[1] : (_Float16)0;
#endif
#if __has_builtin(__builtin_amdgcn_fdot2)
      ga[r] = __builtin_amdgcn_fdot2(tt, w2v, ga[r], false);
#else
      ga[r] += (float)tt[0] * (float)w2v[0] + (float)tt[1] * (float)w2v[1];
#endif
    }
  }
#pragma unroll
  for (int r = 0; r < 16; ++r) {
    float v = ga[r];
    v += __shfl_xor(v, 1, 64);
    v += __shfl_xor(v, 2, 64);
    if (hq == 0 && r0 + r < EB_)
      a.gv[(size_t)(r0 + r) * 256 + c0 + lloc] = v + a.gb2[c0 + lloc];
  }
}

__global__ __launch_bounds__(256, 1) void scan_kernel(SK a) {
  __shared__ __align__(16) short As[16 * 1024];  // 32 KB, reused per phase
  __shared__ float ztile[16][64];
  __shared__ int sRel;
  const int wg = blockIdx.x, tid = threadIdx.x;
  const int lane = tid & 63, wv = tid >> 6, l15 = lane & 15, l4 = lane >> 4;
  const int rb4 = wg >> 2, c04 = (wg & 3) * 64, r04 = rb4 * 16;
  const int e40 = r04 / 50, e41 = (r04 + 15) / 50;
  float lr0 = 0.f, lr1 = 0.f;
  unsigned ph = 0;

  for (int t = 0; t < T_; ++t) {
    // ---- PHI1: zP = (zhi+zlo) @ Wz(hi/lo) + axw[t] (56 WGs) ----
    if (wg < 56) {
      short* Ah = As;
      short* Al = As + 4096;
      const int e = wg >> 3, sub = wg & 7, rb = sub >> 1, nb = (sub & 1) * 128;
      const int r0 = rb * 13;
      const int nrows = (50 - r0 < 13) ? (50 - r0) : 13;
      const short* zh = (const short*)a.zhi + (size_t)(e * 50 + r0) * 256;
      const short* zl = (const short*)a.zlo + (size_t)(e * 50 + r0) * 256;
#pragma unroll
      for (int i = 0; i < 2; ++i) {
        const int lin = tid + i * 256, row = lin >> 5, ck = lin & 31;
        s8v vh = {}, vl = {};
        if (row < nrows) {
          vh = *(const s8v*)(zh + row * 256 + ck * 8);
          vl = *(const s8v*)(zl + row * 256 + ck * 8);
        }
        *(s8v*)(Ah + row * 256 + lswz(row, ck)) = vh;
        *(s8v*)(Al + row * 256 + lswz(row, ck)) = vl;
      }
      __syncthreads();
      const short* Bh = (const short*)a.wzh + (size_t)e * 65536;
      const short* Bl = (const short*)a.wzl + (size_t)e * 65536;
      f32x4 acc[2] = {};
#pragma unroll
      for (int kt = 0; kt < 8; ++kt) {
        const int ck = kt * 4 + l4;
        const s8v ah = *(const s8v*)(Ah + l15 * 256 + lswz(l15, ck));
        const s8v al = *(const s8v*)(Al + l15 * 256 + lswz(l15, ck));
#pragma unroll
        for (int nt = 0; nt < 2; ++nt) {
          const int ng = nb + wv * 32 + nt * 16;
          const size_t bo = ((size_t)(ng >> 4) * 8 + kt) * 512 + lane * 8;
          const s8v bh = *(const s8v*)(Bh + bo);
          const s8v bl = *(const s8v*)(Bl + bo);
          acc[nt] = MFMA(ah, bh, acc[nt], 0, 0, 0);
          acc[nt] = MFMA(al, bh, acc[nt], 0, 0, 0);
          acc[nt] = MFMA(ah, bl, acc[nt], 0, 0, 0);
        }
      }
#pragma unroll
      for (int nt = 0; nt < 2; ++nt) {
        const int col = nb + wv * 32 + nt * 16 + l15;
#pragma unroll
        for (int j = 0; j < 4; ++j) {
          const int row = l4 * 4 + j;
          if (row < nrows) {
            const int gr = e * 50 + r0 + row;
            const float v = acc[nt][j] +
                a.axw[((size_t)e * TB_ + t * 50 + r0 + row) * 256 + col];
            a.zP[(size_t)gr * 256 + col] = v;
            a.zPb[(size_t)gr * 256 + col] = __float2bfloat16(v);
          }
        }
      }
    }
    gsync(a.bar, ++ph, tid, wg, &sRel);

    // ---- PHI2: fh1 = relu(zPb @ W1) (176 WGs) ; g-tiles 0..79 (80 WGs) ----
    if (wg < 176) {
      const int rb = wg >> 3, nb = (wg & 7) * 256, r0 = rb * 16;
#pragma unroll
      for (int i = 0; i < 2; ++i) {
        const int lin = tid + i * 256, row = lin >> 5, ck = lin & 31;
        s8v v = {};
        if (r0 + row < EB_)
          v = *(const s8v*)((const short*)a.zPb + (size_t)(r0 + row) * 256 + ck * 8);
        *(s8v*)(As + row * 256 + lswz(row, ck)) = v;
      }
      __syncthreads();
      f32x4 acc[4] = {};
#pragma unroll
      for (int kt = 0; kt < 8; ++kt) {
        const int ck = kt * 4 + l4;
        const s8v av = *(const s8v*)(As + l15 * 256 + lswz(l15, ck));
#pragma unroll
        for (int nt = 0; nt < 4; ++nt) {
          const int ng = nb + wv * 64 + nt * 16;
          const s8v b = *(const s8v*)((const short*)a.w1f +
                                      ((size_t)(ng >> 4) * 8 + kt) * 512 + lane * 8);
          acc[nt] = MFMA(av, b, acc[nt], 0, 0, 0);
        }
      }
#pragma unroll
      for (int nt = 0; nt < 4; ++nt) {
        const int col = nb + wv * 64 + nt * 16 + l15;
        const float bv = (col < 1024) ? a.fb1[col] : a.hb1[col - 1024];
#pragma unroll
        for (int j = 0; j < 4; ++j) {
          const int row = r0 + l4 * 4 + j;
          if (row < EB_)
            a.fh1[(size_t)row * 2048 + col] = __float2bfloat16(fmaxf(acc[nt][j] + bv, 0.f));
        }
      }
    } else {
      const int gt = wg - 176;
      if (gt < 80) g_tile(a, gt, tid);
    }
    gsync(a.bar, ++ph, tid, wg, &sRel);

    // ---- PHI3: fh2 = tanh(fh1 @ W2) (176 WGs) ; g-tiles 80..87 ----
    if (wg < 176) {
      const int rb = wg >> 3, nbl = wg & 7, nb = nbl * 256, r0 = rb * 16;
      const int half = (nbl >= 4) ? 1024 : 0;
#pragma unroll
      for (int i = 0; i < 8; ++i) {
        const int lin = tid + i * 256, row = lin >> 7, ck = lin & 127;
        s8v v = {};
        if (r0 + row < EB_)
          v = *(const s8v*)((const short*)a.fh1 + (size_t)(r0 + row) * 2048 + half + ck * 8);
        *(s8v*)(As + row * 1024 + lswz(row, ck)) = v;
      }
      __syncthreads();
      f32x4 acc[4] = {};
#pragma unroll 4
      for (int kt = 0; kt < 32; ++kt) {
        const int ck = kt * 4 + l4;
        const s8v av = *(const s8v*)(As + l15 * 1024 + lswz(l15, ck));
#pragma unroll
        for (int nt = 0; nt < 4; ++nt) {
          const int ng = nb + wv * 64 + nt * 16;
          const s8v b = *(const s8v*)((const short*)a.w2f +
                                      ((size_t)(ng >> 4) * 32 + kt) * 512 + lane * 8);
          acc[nt] = MFMA(av, b, acc[nt], 0, 0, 0);
        }
      }
#pragma unroll
      for (int nt = 0; nt < 4; ++nt) {
        const int col = nb + wv * 64 + nt * 16 + l15;
        const float bv = half ? a.hb2[col - 1024] : a.fb2[col];
#pragma unroll
        for (int j = 0; j < 4; ++j) {
          const int row = r0 + l4 * 4 + j;
          if (row < EB_)
            a.fh2[(size_t)row * 2048 + col] = __float2bfloat16(tanhf(acc[nt][j] + bv));
        }
      }
    } else {
      const int gt = 80 + (wg - 176);
      if (gt < 88) g_tile(a, gt, tid);
    }
    gsync(a.bar, ++ph, tid, wg, &sRel);

    // ---- PHI4: fv/hv GEMM + epilogue (88 WGs) ----
    if (wg < 88) {
#pragma unroll
      for (int i = 0; i < 4; ++i) {
        const int lin = tid + i * 256, row = lin >> 6, col = lin & 63;
        ztile[row][col] = (r04 + row < EB_) ? a.zP[(size_t)(r04 + row) * 256 + c04 + col] : 1.0f;
      }
      f32x4 accF = {}, accH = {};
#pragma unroll
      for (int fb = 0; fb < 2; ++fb) {
        __syncthreads();
#pragma unroll
        for (int i = 0; i < 8; ++i) {
          const int lin = tid + i * 256, row = lin >> 7, ck = lin & 127;
          s8v v = {};
          if (r04 + row < EB_)
            v = *(const s8v*)((const short*)a.fh2 + (size_t)(r04 + row) * 2048 + fb * 1024 + ck * 8);
          *(s8v*)(As + row * 1024 + lswz(row, ck)) = v;
        }
        __syncthreads();
        const int ng = fb * 256 + c04 + wv * 16;
        f32x4 acc = {};
#pragma unroll 4
        for (int kt = 0; kt < 32; ++kt) {
          const int ck = kt * 4 + l4;
          const s8v av = *(const s8v*)(As + l15 * 1024 + lswz(l15, ck));
          const s8v b = *(const s8v*)((const short*)a.w3f +
                                      ((size_t)(ng >> 4) * 32 + kt) * 512 + lane * 8);
          acc = MFMA(av, b, acc, 0, 0, 0);
        }
        if (fb) accH = acc; else accF = acc;
      }
      const int col = c04 + wv * 16 + l15;
      const float fb3v = a.fb3[col], hb3v = a.hb3[col];
#pragma unroll
      for (int j = 0; j < 4; ++j) {
        const int rl = l4 * 4 + j, row = r04 + rl;
        if (row < EB_) {
          const float fv = accF[j] + fb3v;
          const float hv = accH[j] + hb3v;
          const float gvv = a.gv[(size_t)row * 256 + col];
          const float u = (fv - hv) / gvv;
          if (row / 50 == e40) lr0 += u * u; else lr1 += u * u;
          const float znew = ztile[rl][wv * 16 + l15] + 0.1f * fv +
              gvv * (SQRTH * a.dw[(size_t)t * (EB_ * 256) + (size_t)row * 256 + col]);
          const bf16 h = __float2bfloat16(znew);
          const size_t zi = (size_t)row * 256 + col;
          a.zhi[zi] = h;
          a.zlo[zi] = __float2bfloat16(znew - __bfloat162float(h));
          const int e = row / 50, b = row - e * 50;
          a.zs_bf[((size_t)e * TB_ + t * 50 + b) * 256 + col] = h;
        }
      }
    }
    gsync(a.bar, ++ph, tid, wg, &sRel);
  }

  // register-accumulated lr: one atomic per wave
  if (wg < 88) {
#pragma unroll
    for (int o = 32; o; o >>= 1) {
      lr0 += __shfl_xor(lr0, o, 64);
      lr1 += __shfl_xor(lr1, o, 64);
    }
    if (lane == 0) {
      atomicAdd(&a.logqp[e40], 0.001f * lr0);
      if (e41 != e40 && e41 < E_) atomicAdd(&a.logqp[e41], 0.001f * lr1);
    }
  }
}

__global__ void init_kernel(float* logqp, unsigned* bar) {
  const int i = threadIdx.x;
  if (i < E_) logqp[i] = 0.f;
  for (int j = i; j < 8736; j += 256) bar[j] = 0u;
}

extern "C" void kernel_launch(void* const* d_in, const int* in_sizes, int n_in,
                              void* d_out, int out_size, void* d_ws, size_t ws_size,
                              hipStream_t stream) {
  (void)in_sizes; (void)n_in; (void)out_size;
  const float* enc_w1 = (const float*)d_in[0];
  const float* enc_b1 = (const float*)d_in[1];
  const float* enc_w2 = (const float*)d_in[2];
  const float* enc_b2 = (const float*)d_in[3];
  const float* enc_w3 = (const float*)d_in[4];
  const float* enc_b3 = (const float*)d_in[5];
  const float* qz0_w  = (const float*)d_in[6];
  const float* qz0_b  = (const float*)d_in[7];
  const float* act_w  = (const float*)d_in[8];
  const float* act_b  = (const float*)d_in[9];
  const float* proj_w1 = (const float*)d_in[10];
  const float* proj_b1 = (const float*)d_in[11];
  const float* proj_w2 = (const float*)d_in[12];
  const float* proj_b2 = (const float*)d_in[13];
  const float* proj_w3 = (const float*)d_in[14];
  const float* proj_b3 = (const float*)d_in[15];
  const float* f_w1 = (const float*)d_in[16];
  const float* f_b1 = (const float*)d_in[17];
  const float* f_w2 = (const float*)d_in[18];
  const float* f_b2 = (const float*)d_in[19];
  const float* f_w3 = (const float*)d_in[20];
  const float* f_b3 = (const float*)d_in[21];
  const float* h_w1 = (const float*)d_in[22];
  const float* h_b1 = (const float*)d_in[23];
  const float* h_w2 = (const float*)d_in[24];
  const float* h_b2 = (const float*)d_in[25];
  const float* h_w3 = (const float*)d_in[26];
  const float* h_b3 = (const float*)d_in[27];
  const float* g_w1 = (const float*)d_in[28];
  const float* g_b1 = (const float*)d_in[29];
  const float* g_w2 = (const float*)d_in[30];
  const float* g_b2 = (const float*)d_in[31];
  const float* pz0_mean   = (const float*)d_in[32];
  const float* pz0_logstd = (const float*)d_in[33];
  const float* xs      = (const float*)d_in[34];
  const float* actions = (const float*)d_in[35];
  const float* eps_z0  = (const float*)d_in[36];
  const float* dw      = (const float*)d_in[37];

  float* out = (float*)d_out;
  float* logqp = out;
  float* pred = out + E_;

  char* base = (char*)d_ws;
  size_t off = 0;
  auto alloc = [&](size_t bytes) {
    void* p = base + off;
    off = (off + bytes + 255) & ~(size_t)255;
    return p;
  };
  bf16* zhi    = (bf16*)alloc((size_t)EB_ * 256 * 2);
  bf16* zlo    = (bf16*)alloc((size_t)EB_ * 256 * 2);
  float* zP    = (float*)alloc((size_t)EB_ * 256 * 4);
  bf16* zPb    = (bf16*)alloc((size_t)EB_ * 256 * 2);
  bf16* fh1    = (bf16*)alloc((size_t)EB_ * 2048 * 2);
  bf16* fh2    = (bf16*)alloc((size_t)EB_ * 2048 * 2);
  float* gvb   = (float*)alloc((size_t)EB_ * 256 * 4);
  bf16* zs_bf  = (bf16*)alloc((size_t)E_ * T_ * B_ * 256 * 2);
  float* axw   = (float*)alloc((size_t)E_ * TB_ * 256 * 4);
  bf16* ax_bf  = (bf16*)alloc((size_t)E_ * TB_ * 192 * 2);
  bf16* waxT   = (bf16*)alloc((size_t)E_ * 256 * 192 * 2);
  bf16* wzh    = (bf16*)alloc((size_t)E_ * 65536 * 2);
  bf16* wzl    = (bf16*)alloc((size_t)E_ * 65536 * 2);
  bf16* w1f    = (bf16*)alloc((size_t)2048 * 256 * 2);
  bf16* w2f    = (bf16*)alloc((size_t)2048 * 1024 * 2);
  bf16* w3f    = (bf16*)alloc((size_t)512 * 1024 * 2);
  _Float16* gpk = (_Float16*)alloc((size_t)256 * 3 * 1024 * 2);
  unsigned* bar = (unsigned*)alloc(8736 * 4);
  bf16* xs_bf  = (bf16*)alloc((size_t)E_ * TB_ * D_ * 2);
  bf16* ew1T = (bf16*)alloc((size_t)E_ * D_ * H_ * 2);
  bf16* ew2T = (bf16*)alloc((size_t)E_ * H_ * H_ * 2);
  bf16* ew3T = (bf16*)alloc((size_t)E_ * H_ * C_ * 2);
  bf16* pw1T = (bf16*)alloc((size_t)E_ * L_ * H_ * 2);
  bf16* pw2T = (bf16*)alloc((size_t)E_ * H_ * H_ * 2);
  bf16* pw3T = (bf16*)alloc((size_t)E_ * H_ * D_ * 2);
  const size_t per_row = (size_t)E_ * (H_ * 2 * 2 + C_ * 4);
  size_t remain = (ws_size > off + 4096) ? (ws_size - off - 4096) : 0;
  int CH = (int)(remain / per_row);
  if (CH > 2500) CH = 2500;
  if (CH < 64) CH = 64;
  bf16* bufA = (bf16*)alloc((size_t)E_ * CH * H_ * 2);
  bf16* bufB = (bf16*)alloc((size_t)E_ * CH * H_ * 2);
  float* bufC = (float*)alloc((size_t)E_ * CH * C_ * 4);

  init_kernel<<<dim3(1), dim3(256), 0, stream>>>(logqp, bar);

  const dim3 cb256(256);
  cvt_kernel<<<dim3((E_ * TB_ * D_ / 4 + 255) / 256), cb256, 0, stream>>>(xs, xs_bf, E_ * TB_ * D_ / 4);
  cvtT_kernel<<<dim3(H_ / 32, D_ / 32, E_), cb256, 0, stream>>>(enc_w1, ew1T, D_, H_, (long)D_ * H_, (long)D_ * H_);
  cvtT_kernel<<<dim3(H_ / 32, H_ / 32, E_), cb256, 0, stream>>>(enc_w2, ew2T, H_, H_, (long)H_ * H_, (long)H_ * H_);
  cvtT_kernel<<<dim3(C_ / 32, H_ / 32, E_), cb256, 0, stream>>>(enc_w3, ew3T, H_, C_, (long)H_ * C_, (long)H_ * C_);
  cvtT_kernel<<<dim3(H_ / 32, L_ / 32, E_), cb256, 0, stream>>>(proj_w1, pw1T, L_, H_, (long)L_ * H_, (long)L_ * H_);
  cvtT_kernel<<<dim3(H_ / 32, H_ / 32, E_), cb256, 0, stream>>>(proj_w2, pw2T, H_, H_, (long)H_ * H_, (long)H_ * H_);
  cvtT_kernel<<<dim3(D_ / 32, H_ / 32, E_), cb256, 0, stream>>>(proj_w3, pw3T, H_, D_, (long)H_ * D_, (long)H_ * D_);
  ax_build<<<dim3((E_ * TB_ * 192 + 255) / 256), cb256, 0, stream>>>(actions, xs, ax_bf);
  waxT_build<<<dim3((E_ * 256 * 192 + 255) / 256), cb256, 0, stream>>>(act_w, waxT);
  packWz<<<dim3((E_ * 65536 + 255) / 256), cb256, 0, stream>>>(act_w, wzh, wzl);
  packW<<<dim3((256 * 1024 + 255) / 256), cb256, 0, stream>>>(f_w1, w1f, 256, 1024);
  packW<<<dim3((256 * 1024 + 255) / 256), cb256, 0, stream>>>(h_w1, w1f + (size_t)1024 * 256, 256, 1024);
  packW<<<dim3((1024 * 1024 + 255) / 256), cb256, 0, stream>>>(f_w2, w2f, 1024, 1024);
  packW<<<dim3((1024 * 1024 + 255) / 256), cb256, 0, stream>>>(h_w2, w2f + (size_t)1024 * 1024, 1024, 1024);
  packW<<<dim3((1024 * 256 + 255) / 256), cb256, 0, stream>>>(f_w3, w3f, 1024, 256);
  packW<<<dim3((1024 * 256 + 255) / 256), cb256, 0, stream>>>(h_w3, w3f + (size_t)256 * 1024, 1024, 256);
  gpack_build<<<dim3((256 * 3 * 1024 + 255) / 256), cb256, 0, stream>>>(g_w1, g_b1, g_w2, gpk);

  BG g;
  for (int e = 0; e < E_; ++e) {
    g.A[e] = ax_bf + (size_t)e * TB_ * 192;
    g.W[e] = waxT + (size_t)e * 256 * 192;
    g.bias[e] = act_b + (size_t)e * 256;
    g.Cf[e] = axw + (size_t)e * TB_ * 256;
  }
  bgemm<128, 0, 0><<<dim3((TB_ + 127) / 128, 2, E_), 256, 0, stream>>>(g, TB_, 192, 192, 192, 256);

  // ---- Phase A ----
  for (int c = 0; c < TB_; c += CH) {
    const int rows = (TB_ - c < CH) ? (TB_ - c) : CH;
    const int mt = (rows + 127) / 128;
    for (int e = 0; e < E_; ++e) {
      g.A[e] = xs_bf + ((size_t)e * TB_ + c) * D_;
      g.W[e] = ew1T + (size_t)e * D_ * H_;
      g.bias[e] = enc_b1 + (size_t)e * H_;
      g.Cb[e] = bufA + (size_t)e * CH * H_;
    }
    bgemm<128, 1, 1><<<dim3(mt, H_ / 128, E_), 256, 0, stream>>>(g, rows, D_, D_, D_, H_);
    for (int e = 0; e < E_; ++e) {
      g.A[e] = bufA + (size_t)e * CH * H_;
      g.W[e] = ew2T + (size_t)e * H_ * H_;
      g.bias[e] = enc_b2 + (size_t)e * H_;
      g.Cb[e] = bufB + (size_t)e * CH * H_;
    }
    bgemm<128, 1, 1><<<dim3(mt, H_ / 128, E_), 256, 0, stream>>>(g, rows, H_, H_, H_, H_);
    for (int e = 0; e < E_; ++e) {
      g.A[e] = bufB + (size_t)e * CH * H_;
      g.W[e] = ew3T + (size_t)e * H_ * C_;
      g.bias[e] = enc_b3 + (size_t)e * C_;
      g.Cf[e] = bufC + (size_t)e * CH * C_;
    }
    bgemm<128, 0, 0><<<dim3(mt, C_ / 128, E_), 256, 0, stream>>>(g, rows, H_, H_, H_, C_);
    qkl_kernel<<<dim3((rows + 15) / 16, E_), 256, 0, stream>>>(
        bufC, rows, c, CH * C_, qz0_w, qz0_b, pz0_mean, pz0_logstd, eps_z0,
        zhi, zlo, logqp);
  }

  // ---- Persistent scan ----
  SK sk;
  sk.wzh = wzh; sk.wzl = wzl; sk.w1f = w1f; sk.w2f = w2f; sk.w3f = w3f;
  sk.gpk = gpk;
  sk.fb1 = f_b1; sk.hb1 = h_b1; sk.fb2 = f_b2; sk.hb2 = h_b2;
  sk.fb3 = f_b3; sk.hb3 = h_b3; sk.gb2 = g_b2;
  sk.axw = axw; sk.dw = dw;
  sk.zP = zP; sk.gv = gvb; sk.zPb = zPb; sk.fh1 = fh1; sk.fh2 = fh2;
  sk.zhi = zhi; sk.zlo = zlo; sk.zs_bf = zs_bf; sk.logqp = logqp; sk.bar = bar;
  void* params[] = {(void*)&sk};
  if (hipLaunchCooperativeKernel((const void*)scan_kernel, dim3(NWG), dim3(256),
                                 params, 0, stream) != hipSuccess) {
    scan_kernel<<<dim3(NWG), dim3(256), 0, stream>>>(sk);
  }

  // ---- Projector ----
  for (int c = 0; c < TB_; c += CH) {
    const int rows = (TB_ - c < CH) ? (TB_ - c) : CH;
    const int mt = (rows + 127) / 128;
    for (int e = 0; e < E_; ++e) {
      g.A[e] = zs_bf + ((size_t)e * T_ * B_ + c) * L_;
      g.W[e] = pw1T + (size_t)e * L_ * H_;
      g.bias[e] = proj_b1 + (size_t)e * H_;
      g.Cb[e] = bufA + (size_t)e * CH * H_;
    }
    bgemm<128, 2, 1><<<dim3(mt, H_ / 128, E_), 256, 0, stream>>>(g, rows, L_, L_, L_, H_);
    for (int e = 0; e < E_; ++e) {
      g.A[e] = bufA + (size_t)e * CH * H_;
      g.W[e] = pw2T + (size_t)e * H_ * H_;
      g.bias[e] = proj_b2 + (size_t)e * H_;
      g.Cb[e] = bufB + (size_t)e * CH * H_;
    }
    bgemm<128, 2, 1><<<dim3(mt, H_ / 128, E_), 256, 0, stream>>>(g, rows, H_, H_, H_, H_);
    for (int e = 0; e < E_; ++e) {
      g.A[e] = bufB + (size_t)e * CH * H_;
      g.W[e] = pw3T + (size_t)e * H_ * D_;
      g.bias[e] = proj_b3 + (size_t)e * D_;
      g.Cf[e] = pred + ((size_t)e * TB_ + c) * D_;
    }
    bgemm<128, 0, 0><<<dim3(mt, D_ / 128, E_), 256, 0, stream>>>(g, rows, H_, H_, H_, D_);
  }
}